// Round 20
// baseline (379.738 us; speedup 1.0000x reference)
//
#include <hip/hip_runtime.h>
#include <math.h>

#define THREADS 256
#define SB 1024           // blocks for hist/scatter passes (chunked edge ranges)
#define BSH 8             // bucket shift: 256 nodes per bucket
#define BSZ 256
#define BMSK 255
#define SEG 2048          // edges per scatter segment (8 per thread)

// ---------------------------------------------------------------------------
// Per-block LDS histograms over node buckets (bucket = 256 nodes).
__global__ void hist_kernel(const int* __restrict__ row, const int* __restrict__ col,
                            int* __restrict__ TU, int E, int NB, int chunk) {
    extern __shared__ int sh[];
    int t = threadIdx.x, b = blockIdx.x;
    for (int k = t; k < 2 * NB; k += THREADS) sh[k] = 0;
    __syncthreads();
    int lo = b * chunk;
    int hi = min(lo + chunk, E);
    for (int e = lo + t; e < hi; e += THREADS) {
        int r = row[e], c = col[e];
        if (r != c) {
            atomicAdd(&sh[r >> BSH], 1);
            atomicAdd(&sh[NB + (c >> BSH)], 1);
        }
    }
    __syncthreads();
    for (int k = t; k < 2 * NB; k += THREADS) TU[k * SB + b] = sh[k];
}

// ---------------------------------------------------------------------------
// Exclusive scan, 1024 entries per block (4 serial per thread + block scan).
__global__ void scan1_kernel(int* __restrict__ data, int* __restrict__ bsum, int n) {
    __shared__ int s[256];
    int t = threadIdx.x;
    int base = blockIdx.x * 1024 + t * 4;
    int a0 = (base + 0 < n) ? data[base + 0] : 0;
    int a1 = (base + 1 < n) ? data[base + 1] : 0;
    int a2 = (base + 2 < n) ? data[base + 2] : 0;
    int a3 = (base + 3 < n) ? data[base + 3] : 0;
    int tsum = a0 + a1 + a2 + a3;
    s[t] = tsum;
    __syncthreads();
    for (int d = 1; d < 256; d <<= 1) {
        int xv = (t >= d) ? s[t - d] : 0;
        __syncthreads();
        s[t] += xv;
        __syncthreads();
    }
    int excl = s[t] - tsum;
    if (base + 0 < n) data[base + 0] = excl;
    if (base + 1 < n) data[base + 1] = excl + a0;
    if (base + 2 < n) data[base + 2] = excl + a0 + a1;
    if (base + 3 < n) data[base + 3] = excl + a0 + a1 + a2;
    if (t == 255) bsum[blockIdx.x] = s[255];
}

__global__ void scan2_kernel(const int* __restrict__ bsum, int* __restrict__ boff, int nb) {
    __shared__ int s[1024];
    int t = threadIdx.x;
    int v = (t < nb) ? bsum[t] : 0;
    s[t] = v;
    __syncthreads();
    for (int d = 1; d < 1024; d <<= 1) {
        int xv = (t >= d) ? s[t - d] : 0;
        __syncthreads();
        s[t] += xv;
        __syncthreads();
    }
    if (t < nb) boff[t] = s[t] - v;
    if (t == nb - 1) boff[nb] = s[t];            // grand total
}

__global__ void scan3_kernel(int* __restrict__ data, const int* __restrict__ boff,
                             int n, int nbk) {
    int i = blockIdx.x * blockDim.x + threadIdx.x;
    if (i < n) data[i] += boff[i >> 10];
    else if (i == n) data[n] = boff[nbk];        // append grand total
}

// ---------------------------------------------------------------------------
// Scatter with segment-local counting sort. Row-half records are PACKED to
// 4 bytes: (local_id<<24) | (float_bits>>9). Col-half records stay 8B.
__global__ void scatter_kernel(const int* __restrict__ row, const int* __restrict__ col,
                               const float* __restrict__ ew,
                               const int* __restrict__ TU,
                               int* __restrict__ rec4, int2* __restrict__ rec8,
                               int E, int NB, int chunk) {
    extern __shared__ int shl[];
    const int nb2 = 2 * NB;                                    // <= 1024
    int* skey  = shl;                                          // [2*SEG]
    int* sval  = skey + 2 * SEG;                               // [2*SEG]
    int* cur   = sval + 2 * SEG;                               // [nb2]
    int* sbase = cur + nb2;                                    // [nb2]
    int* scur  = sbase + nb2;                                  // [nb2]
    int* stmp  = scur + nb2;                                   // [256]
    unsigned short* bid = (unsigned short*)(stmp + 256);       // [2*SEG]

    int t = threadIdx.x, b = blockIdx.x;
    int colbase = TU[NB * SB];
    for (int k = t; k < nb2; k += THREADS)
        cur[k] = TU[k * SB + b] - ((k >= NB) ? colbase : 0);
    int lo = b * chunk;
    int hi = min(lo + chunk, E);

    for (int slo = lo; slo < hi; slo += SEG) {
        int scount = min(SEG, hi - slo);
        for (int k = t; k < nb2; k += THREADS) sbase[k] = 0;
        __syncthreads();

        int er[8], ec[8];
        float ewv[8];
#pragma unroll
        for (int j = 0; j < 8; ++j) {
            er[j] = -1;
            int e = slo + j * THREADS + t;
            if (e < slo + scount) {
                int r = row[e], c = col[e];
                if (r != c) {
                    er[j] = r; ec[j] = c; ewv[j] = ew[e];
                    atomicAdd(&sbase[r >> BSH], 1);
                    atomicAdd(&sbase[NB + (c >> BSH)], 1);
                }
            }
        }
        __syncthreads();

        // exclusive scan of nb2 per-bucket counts (4 serial + 256 block scan)
        int b4 = t * 4;
        int a0 = (b4 + 0 < nb2) ? sbase[b4 + 0] : 0;
        int a1 = (b4 + 1 < nb2) ? sbase[b4 + 1] : 0;
        int a2 = (b4 + 2 < nb2) ? sbase[b4 + 2] : 0;
        int a3 = (b4 + 3 < nb2) ? sbase[b4 + 3] : 0;
        int tsum = a0 + a1 + a2 + a3;
        stmp[t] = tsum;
        __syncthreads();
        for (int d = 1; d < 256; d <<= 1) {
            int xv = (t >= d) ? stmp[t - d] : 0;
            __syncthreads();
            stmp[t] += xv;
            __syncthreads();
        }
        int excl = stmp[t] - tsum;
        int total = stmp[255];
        __syncthreads();
        if (b4 + 0 < nb2) { sbase[b4 + 0] = excl;                scur[b4 + 0] = excl; }
        if (b4 + 1 < nb2) { sbase[b4 + 1] = excl + a0;           scur[b4 + 1] = excl + a0; }
        if (b4 + 2 < nb2) { sbase[b4 + 2] = excl + a0 + a1;      scur[b4 + 2] = excl + a0 + a1; }
        if (b4 + 3 < nb2) { sbase[b4 + 3] = excl + a0 + a1 + a2; scur[b4 + 3] = excl + a0 + a1 + a2; }
        __syncthreads();

        // ranked placement into bucket-ordered staging
#pragma unroll
        for (int j = 0; j < 8; ++j) {
            if (er[j] >= 0) {
                int r = er[j], c = ec[j];
                int wbits = __float_as_int(ewv[j]);
                int k1 = r >> BSH;
                int p1 = atomicAdd(&scur[k1], 1);
                skey[p1] = ((r & BMSK) << 24) | (((unsigned)wbits) >> 9);
                bid[p1] = (unsigned short)k1;
                int k2 = NB + (c >> BSH);
                int p2 = atomicAdd(&scur[k2], 1);
                skey[p2] = (r << BSH) | (c & BMSK);
                sval[p2] = wbits;
                bid[p2] = (unsigned short)k2;
            }
        }
        __syncthreads();

        // cooperative dense write-out (consecutive lanes -> consecutive addrs)
        for (int j = t; j < total; j += THREADS) {
            int k = bid[j];
            int pos = cur[k] + (j - sbase[k]);
            if (k < NB) rec4[pos] = skey[j];
            else        rec8[pos] = make_int2(skey[j], sval[j]);
        }
        __syncthreads();

        for (int k = t; k < nb2; k += THREADS) cur[k] += scur[k] - sbase[k];
        __syncthreads();
    }
}

// ---------------------------------------------------------------------------
// Fused deg-reduce + init over packed 4B row records.
__global__ void degini_kernel(const int* __restrict__ rec4, const int* __restrict__ TU,
                              const float* __restrict__ x,
                              float* __restrict__ dis, float2* __restrict__ tx0,
                              float2* __restrict__ outacc, const float* __restrict__ Wc,
                              int N) {
    __shared__ float acc[BSZ];
    int t = threadIdx.x, bk = blockIdx.x;
    if (t < BSZ) acc[t] = 0.f;
    __syncthreads();
    int s = TU[bk * SB];
    int e = TU[(bk + 1) * SB];
    int i = s + t;
    for (; i + 3 * 1024 < e; i += 4 * 1024) {
        int p0 = rec4[i];
        int p1 = rec4[i + 1024];
        int p2 = rec4[i + 2048];
        int p3 = rec4[i + 3072];
        atomicAdd(&acc[((unsigned)p0) >> 24], __int_as_float((p0 & 0x7FFFFF) << 9));
        atomicAdd(&acc[((unsigned)p1) >> 24], __int_as_float((p1 & 0x7FFFFF) << 9));
        atomicAdd(&acc[((unsigned)p2) >> 24], __int_as_float((p2 & 0x7FFFFF) << 9));
        atomicAdd(&acc[((unsigned)p3) >> 24], __int_as_float((p3 & 0x7FFFFF) << 9));
    }
    for (; i < e; i += 1024) {
        int p = rec4[i];
        atomicAdd(&acc[((unsigned)p) >> 24], __int_as_float((p & 0x7FFFFF) << 9));
    }
    __syncthreads();
    if (t < BSZ) {
        int node = (bk << BSH) + t;
        if (node < N) {
            float d = acc[t];
            dis[node] = (d > 0.f) ? rsqrtf(d) : 0.f;
            float x0 = x[3 * node + 0];
            float x1 = x[3 * node + 1];
            tx0[node] = make_float2(x0, x1);
            outacc[node] = make_float2(x0 * Wc[0] + x1 * Wc[2],
                                       x0 * Wc[1] + x1 * Wc[3]);
        }
    }
}

// ---------------------------------------------------------------------------
// Node-level sort of the col records + norm baking + FUSED PASS-1 PROP.
// Count pass 4-way unrolled; placement pass 2-way interleaved (independent
// dependence chains -> 2x outstanding loads per lane).
__global__ void nodesort_kernel(const int2* __restrict__ rec8, const int* __restrict__ TU,
                                const float* __restrict__ dis, const float2* __restrict__ hA,
                                int2* __restrict__ srec, int* __restrict__ rowstart,
                                float2* __restrict__ vout, float2* __restrict__ outacc,
                                const float* __restrict__ Wc, int NB, int N) {
    __shared__ int cnt[BSZ], cur[BSZ], stmp[BSZ];
    __shared__ float disc[BSZ], ax[BSZ], ay[BSZ];
    int t = threadIdx.x, bk = blockIdx.x;
    int colbase = TU[NB * SB];
    if (t < BSZ) {
        cnt[t] = 0;
        ax[t] = 0.f;
        ay[t] = 0.f;
        int node = (bk << BSH) + t;
        disc[t] = (node < N) ? dis[node] : 0.f;
    }
    __syncthreads();
    int s = TU[(NB + bk) * SB] - colbase;
    int e = TU[(NB + bk + 1) * SB] - colbase;

    // count pass (4-way unroll, independent loads)
    {
        int i = s + t;
        for (; i + 3 * 1024 < e; i += 4 * 1024) {
            int a = rec8[i].x;
            int b = rec8[i + 1024].x;
            int c = rec8[i + 2048].x;
            int d = rec8[i + 3072].x;
            atomicAdd(&cnt[a & BMSK], 1);
            atomicAdd(&cnt[b & BMSK], 1);
            atomicAdd(&cnt[c & BMSK], 1);
            atomicAdd(&cnt[d & BMSK], 1);
        }
        for (; i < e; i += 1024) atomicAdd(&cnt[rec8[i].x & BMSK], 1);
    }
    __syncthreads();
    if (t < BSZ) stmp[t] = cnt[t];
    __syncthreads();
    for (int d = 1; d < BSZ; d <<= 1) {
        int xv = (t >= d && t < BSZ) ? stmp[t - d] : 0;
        __syncthreads();
        if (t < BSZ) stmp[t] += xv;
        __syncthreads();
    }
    if (t < BSZ) {
        int g = s + stmp[t] - cnt[t];
        cur[t] = g;
        rowstart[(bk << BSH) + t] = g;
        if (bk == NB - 1 && t == 0) rowstart[NB << BSH] = e;
    }
    __syncthreads();

    // placement + fused prop (2-way interleave, independent chains)
    {
        int i = s + t;
        for (; i + 1024 < e; i += 2048) {
            int2 p0 = rec8[i];
            int2 p1 = rec8[i + 1024];
            int cl0 = p0.x & BMSK, r0 = ((unsigned)p0.x) >> BSH;
            int cl1 = p1.x & BMSK, r1 = ((unsigned)p1.x) >> BSH;
            float w0 = -dis[r0] * __int_as_float(p0.y) * disc[cl0];
            float w1 = -dis[r1] * __int_as_float(p1.y) * disc[cl1];
            float2 h0 = hA[r0];
            float2 h1 = hA[r1];
            int pos0 = atomicAdd(&cur[cl0], 1);
            int pos1 = atomicAdd(&cur[cl1], 1);
            srec[pos0] = make_int2(r0, __float_as_int(w0));
            srec[pos1] = make_int2(r1, __float_as_int(w1));
            atomicAdd(&ax[cl0], w0 * h0.x);
            atomicAdd(&ay[cl0], w0 * h0.y);
            atomicAdd(&ax[cl1], w1 * h1.x);
            atomicAdd(&ay[cl1], w1 * h1.y);
        }
        for (; i < e; i += 1024) {
            int2 p = rec8[i];
            int cl = p.x & BMSK;
            int r = ((unsigned)p.x) >> BSH;
            float w = -dis[r] * __int_as_float(p.y) * disc[cl];
            int pos = atomicAdd(&cur[cl], 1);
            srec[pos] = make_int2(r, __float_as_int(w));
            float2 hv = hA[r];
            atomicAdd(&ax[cl], w * hv.x);
            atomicAdd(&ay[cl], w * hv.y);
        }
    }
    __syncthreads();
    if (t < BSZ) {
        int node = (bk << BSH) + t;
        if (node < N) {
            float2 v = make_float2(ax[t], ay[t]);       // Tx1 (k=1: no recurrence)
            vout[node] = v;
            float2 o = outacc[node];
            o.x += v.x * Wc[4 + 0] + v.y * Wc[4 + 2];   // Wc[1]
            o.y += v.x * Wc[4 + 1] + v.y * Wc[4 + 3];
            outacc[node] = o;
        }
    }
}

// ---------------------------------------------------------------------------
// Propagation with fused Chebyshev update (k>=2): 16 lanes per TWO adjacent
// nodes, fully independent dual chains (4 outstanding loads/lane), width-16
// shuffle reduce per node.
__global__ void gather_kernel(const int2* __restrict__ srec, const int* __restrict__ rowstart,
                              const float2* __restrict__ h, const float2* __restrict__ tx0,
                              float2* __restrict__ vout, float2* __restrict__ outacc,
                              const float* __restrict__ Wc, int k, int N) {
    int grp = blockIdx.x * (THREADS / 16) + (threadIdx.x >> 4);
    int lane = threadIdx.x & 15;
    int nA = 2 * grp;
    if (nA >= N) return;
    int nB = nA + 1;
    bool hasB = (nB < N);
    int sA = rowstart[nA], eA = rowstart[nA + 1];
    int sB = hasB ? eA : 0, eB = hasB ? rowstart[nB + 1] : 0;
    float axA = 0.f, ayA = 0.f, axB = 0.f, ayB = 0.f;
    int iA = sA + lane, iB = sB + lane;
    while (iA < eA && iB < eB) {
        int2 pA = srec[iA];
        int2 pB = srec[iB];
        float2 hvA = h[pA.x];
        float2 hvB = h[pB.x];
        float wA = __int_as_float(pA.y);
        float wB = __int_as_float(pB.y);
        axA = fmaf(wA, hvA.x, axA); ayA = fmaf(wA, hvA.y, ayA);
        axB = fmaf(wB, hvB.x, axB); ayB = fmaf(wB, hvB.y, ayB);
        iA += 16; iB += 16;
    }
    for (; iA < eA; iA += 16) {
        int2 p = srec[iA];
        float2 hv = h[p.x];
        float w = __int_as_float(p.y);
        axA = fmaf(w, hv.x, axA); ayA = fmaf(w, hv.y, ayA);
    }
    for (; iB < eB; iB += 16) {
        int2 p = srec[iB];
        float2 hv = h[p.x];
        float w = __int_as_float(p.y);
        axB = fmaf(w, hv.x, axB); ayB = fmaf(w, hv.y, ayB);
    }
    for (int off = 8; off > 0; off >>= 1) {
        axA += __shfl_down(axA, off, 16);
        ayA += __shfl_down(ayA, off, 16);
        axB += __shfl_down(axB, off, 16);
        ayB += __shfl_down(ayB, off, 16);
    }
    if (lane == 0) {
        float2 v = make_float2(axA, ayA);
        if (tx0) {
            float2 tv = tx0[nA];
            v.x = 2.f * v.x - tv.x;
            v.y = 2.f * v.y - tv.y;
        }
        vout[nA] = v;
        float2 o = outacc[nA];
        o.x += v.x * Wc[4 * k + 0] + v.y * Wc[4 * k + 2];
        o.y += v.x * Wc[4 * k + 1] + v.y * Wc[4 * k + 3];
        outacc[nA] = o;
        if (hasB) {
            float2 vB = make_float2(axB, ayB);
            if (tx0) {
                float2 tv = tx0[nB];
                vB.x = 2.f * vB.x - tv.x;
                vB.y = 2.f * vB.y - tv.y;
            }
            vout[nB] = vB;
            float2 oB = outacc[nB];
            oB.x += vB.x * Wc[4 * k + 0] + vB.y * Wc[4 * k + 2];
            oB.y += vB.x * Wc[4 * k + 1] + vB.y * Wc[4 * k + 3];
            outacc[nB] = oB;
        }
    }
}

// ---------------------------------------------------------------------------
// Full-atomic fallback kernels (only if workspace is too small).
__global__ void zero_kernel(float* __restrict__ p, int n) {
    int i = blockIdx.x * blockDim.x + threadIdx.x;
    if (i < n) p[i] = 0.f;
}
__global__ void zerof2_kernel(float2* __restrict__ p, int n) {
    int i = blockIdx.x * blockDim.x + threadIdx.x;
    if (i < n) p[i] = make_float2(0.f, 0.f);
}
__global__ void deg_at_kernel(const int* __restrict__ row, const int* __restrict__ col,
                              const float* __restrict__ ew, float* __restrict__ deg, int E) {
    int e = blockIdx.x * blockDim.x + threadIdx.x;
    if (e >= E) return;
    int r = row[e], c = col[e];
    if (r != c) atomicAdd(&deg[r], ew[e]);
}
__global__ void init_at_kernel(const float* __restrict__ x, float* __restrict__ deg,
                               float2* __restrict__ tx0, float2* __restrict__ outacc,
                               const float* __restrict__ Wc, int N) {
    int i = blockIdx.x * blockDim.x + threadIdx.x;
    if (i >= N) return;
    float d = deg[i];
    deg[i] = (d > 0.f) ? rsqrtf(d) : 0.f;
    float x0 = x[3 * i + 0];
    float x1 = x[3 * i + 1];
    tx0[i] = make_float2(x0, x1);
    outacc[i] = make_float2(x0 * Wc[0] + x1 * Wc[2],
                            x0 * Wc[1] + x1 * Wc[3]);
}
__global__ void prop_kernel(const int* __restrict__ row, const int* __restrict__ col,
                            const float* __restrict__ ew, const float* __restrict__ dis,
                            const float2* __restrict__ h, float2* __restrict__ o, int E) {
    int e = blockIdx.x * blockDim.x + threadIdx.x;
    if (e >= E) return;
    int r = row[e], c = col[e];
    if (r == c) return;
    float w = -dis[r] * ew[e] * dis[c];
    if (w == 0.f) return;
    float2 hv = h[r];
    atomicAdd(&o[c].x, w * hv.x);
    atomicAdd(&o[c].y, w * hv.y);
}
__global__ void cheb_at_kernel(float2* __restrict__ raw, const float2* __restrict__ tx0,
                               float2* __restrict__ outacc, const float* __restrict__ Wc,
                               int k, int N) {
    int i = blockIdx.x * blockDim.x + threadIdx.x;
    if (i >= N) return;
    float2 v = raw[i];
    if (tx0) {
        float2 t = tx0[i];
        v.x = 2.f * v.x - t.x;
        v.y = 2.f * v.y - t.y;
        raw[i] = v;
    }
    float2 o = outacc[i];
    o.x += v.x * Wc[4 * k + 0] + v.y * Wc[4 * k + 2];
    o.y += v.x * Wc[4 * k + 1] + v.y * Wc[4 * k + 3];
    outacc[i] = o;
}

// ---------------------------------------------------------------------------
// Fused epilogue (3 kernels): per-block (max, sum-of-exp) via LSE rescale.
__global__ void u_ms_kernel(const float* __restrict__ x, const float2* __restrict__ outacc,
                            const float* __restrict__ cb, const float* __restrict__ W,
                            const float* __restrict__ b, float* __restrict__ U,
                            float* __restrict__ part2, int N) {
    __shared__ float sm[THREADS / 64];
    __shared__ float bmax;
    int i = blockIdx.x * blockDim.x + threadIdx.x;
    int t = threadIdx.x;
    float u = -INFINITY;
    if (i < N) {
        float2 o = outacc[i];
        float h0 = fmaxf(o.x + cb[0], 0.f);
        float h1 = fmaxf(o.y + cb[1], 0.f);
        u = x[3 * i + 2] * W[0] + h0 * W[1] + h1 * W[2] + b[0];
        U[i] = u;
    }
    float mv = u;
    for (int off = 32; off > 0; off >>= 1) mv = fmaxf(mv, __shfl_down(mv, off));
    if ((t & 63) == 0) sm[t >> 6] = mv;
    __syncthreads();
    if (t == 0) {
        float m = sm[0];
        for (int w = 1; w < THREADS / 64; ++w) m = fmaxf(m, sm[w]);
        bmax = m;
    }
    __syncthreads();
    float bm = bmax;
    float e = (i < N) ? expf(u - bm) : 0.f;
    for (int off = 32; off > 0; off >>= 1) e += __shfl_down(e, off);
    __syncthreads();
    if ((t & 63) == 0) sm[t >> 6] = e;
    __syncthreads();
    if (t == 0) {
        float s = sm[0];
        for (int w = 1; w < THREADS / 64; ++w) s += sm[w];
        part2[2 * blockIdx.x]     = bm;
        part2[2 * blockIdx.x + 1] = s;
    }
}

__global__ void red_ms_kernel(const float* __restrict__ part2, int n,
                              float* __restrict__ scal) {
    __shared__ float sm[16];
    __shared__ float gmax;
    int t = threadIdx.x;
    float m = -INFINITY;
    for (int i = t; i < n; i += blockDim.x) m = fmaxf(m, part2[2 * i]);
    for (int off = 32; off > 0; off >>= 1) m = fmaxf(m, __shfl_down(m, off));
    int wid = t >> 6;
    if ((t & 63) == 0) sm[wid] = m;
    __syncthreads();
    if (t == 0) {
        float r = sm[0];
        int nw = blockDim.x >> 6;
        for (int w = 1; w < nw; ++w) r = fmaxf(r, sm[w]);
        gmax = r;
    }
    __syncthreads();
    float M = gmax;
    float s = 0.f;
    for (int i = t; i < n; i += blockDim.x) s += part2[2 * i + 1] * expf(part2[2 * i] - M);
    for (int off = 32; off > 0; off >>= 1) s += __shfl_down(s, off);
    __syncthreads();
    if ((t & 63) == 0) sm[wid] = s;
    __syncthreads();
    if (t == 0) {
        float r = sm[0];
        int nw = blockDim.x >> 6;
        for (int w = 1; w < nw; ++w) r += sm[w];
        scal[0] = M;
        scal[1] = 1.f / r;
    }
}

__global__ void out_kernel(const float* __restrict__ U, const float* __restrict__ scal,
                           float* __restrict__ out, int N) {
    int i = blockIdx.x * blockDim.x + threadIdx.x;
    if (i < N) out[i] = expf(U[i] - scal[0]) * scal[1];
}

// ---------------------------------------------------------------------------
extern "C" void kernel_launch(void* const* d_in, const int* in_sizes, int n_in,
                              void* d_out, int out_size, void* d_ws, size_t ws_size,
                              hipStream_t stream) {
    (void)n_in; (void)out_size;
    const float* x    = (const float*)d_in[0];
    const int*   eidx = (const int*)d_in[1];     // int32 per harness contract
    const float* ew   = (const float*)d_in[2];
    const float* Wc   = (const float*)d_in[3];
    const float* cb   = (const float*)d_in[4];
    const float* W    = (const float*)d_in[5];
    const float* b    = (const float*)d_in[6];
    float*       out  = (float*)d_out;

    const int N = in_sizes[0] / 3;
    const int E = in_sizes[2];
    const int K = in_sizes[3] / 4;
    const int* row = eidx;
    const int* col = eidx + E;

    const int NB    = (N + BMSK) >> BSH;         // 256-node buckets
    const int nb2   = 2 * NB;
    const int n2    = nb2 * SB;                  // unified count-table length
    const int nblk  = (n2 + 1023) / 1024;        // scan1 blocks (1024/block)
    const int chunk = (E + SB - 1) / SB;
    const int Npad  = NB << BSH;

    char* ws = (char*)d_ws;
    size_t off = 0;
    auto take = [&](size_t bytes) -> void* {
        void* p = ws + off;
        off = (off + bytes + 255) & ~(size_t)255;
        return p;
    };

    float*  dis      = (float*)take((size_t)N * 4);
    float2* A        = (float2*)take((size_t)N * 8);
    float2* B        = (float2*)take((size_t)N * 8);
    float2* C        = (float2*)take((size_t)N * 8);
    float2* outacc   = (float2*)take((size_t)N * 8);
    float*  U        = (float*)take((size_t)N * 4);
    float*  part     = (float*)take(8192 * 4);
    float*  scal     = (float*)take(64 * 4);
    int*    TU       = (int*)take((size_t)(n2 + 1) * 4);
    int*    bsum     = (int*)take(1024 * 4);
    int*    boff     = (int*)take(1025 * 4);
    int*    rowstart = (int*)take((size_t)(Npad + 1) * 4);
    int*    recbase  = (int*)take((size_t)2 * E * 8);
    // Aliased layout within recbase (2E*8 bytes):
    //   rec4 = [0, 4E)        packed row records (dead after degini)
    //   srec = [0, 8E)        node-sorted col records (written by nodesort)
    //   rec8 = [8E, 16E)      bucket-sorted col records
    int*  rec4 = recbase;
    int2* srec = (int2*)recbase;
    int2* rec8 = ((int2*)recbase) + E;

    const bool bucket_ok = (nb2 <= 1024) && (nblk <= 1024) && (N < (1 << 23)) &&
                           (off <= ws_size) && (K >= 2);

    const int eb = (E + THREADS - 1) / THREADS;
    const int nb = (N + THREADS - 1) / THREADS;

    if (bucket_ok) {
        // dynamic LDS for scatter (must match device-side layout)
        size_t scat_lds = (size_t)(4 * SEG) * 4      // skey + sval
                        + (size_t)(3 * nb2) * 4      // cur/sbase/scur
                        + 256 * 4                    // stmp
                        + (size_t)(2 * SEG) * 2;     // bid ushort

        hist_kernel<<<SB, THREADS, nb2 * 4, stream>>>(row, col, TU, E, NB, chunk);
        scan1_kernel<<<nblk, 256, 0, stream>>>(TU, bsum, n2);
        scan2_kernel<<<1, 1024, 0, stream>>>(bsum, boff, nblk);
        scan3_kernel<<<(n2 + 256) / 256, 256, 0, stream>>>(TU, boff, n2, nblk);
        scatter_kernel<<<SB, THREADS, scat_lds, stream>>>(row, col, ew, TU, rec4, rec8,
                                                          E, NB, chunk);
        // fused deg-reduce + init (packed row records)
        degini_kernel<<<NB, 1024, 0, stream>>>(rec4, TU, x, dis, A, outacc, Wc, N);
        // node sort + norm bake + fused pass-1 prop + cheb k=1 (rec8 -> srec)
        nodesort_kernel<<<NB, 1024, 0, stream>>>(rec8, TU, dis, A, srec, rowstart,
                                                 B, outacc, Wc, NB, N);

        const int ngrp = (N + 1) / 2;
        const int gb = (ngrp + (THREADS / 16) - 1) / (THREADS / 16);
        // k = 2..K-1, Chebyshev update fused into gather epilogue
        float2 *t0 = A, *t1 = B, *fr = C;
        for (int k = 2; k < K; ++k) {
            gather_kernel<<<gb, THREADS, 0, stream>>>(srec, rowstart, t1, t0, fr, outacc, Wc, k, N);
            float2* n0 = t1; float2* n1 = fr; float2* nf = t0;
            t0 = n0; t1 = n1; fr = nf;
        }
    } else {
        // ---- full-atomic fallback ----
        zero_kernel<<<nb, THREADS, 0, stream>>>(dis, N);
        deg_at_kernel<<<eb, THREADS, 0, stream>>>(row, col, ew, dis, E);
        init_at_kernel<<<nb, THREADS, 0, stream>>>(x, dis, A, outacc, Wc, N);
        zerof2_kernel<<<nb, THREADS, 0, stream>>>(B, N);
        prop_kernel<<<eb, THREADS, 0, stream>>>(row, col, ew, dis, A, B, E);
        cheb_at_kernel<<<nb, THREADS, 0, stream>>>(B, (const float2*)nullptr, outacc, Wc, 1, N);
        float2 *t0 = A, *t1 = B, *fr = C;
        for (int k = 2; k < K; ++k) {
            zerof2_kernel<<<nb, THREADS, 0, stream>>>(fr, N);
            prop_kernel<<<eb, THREADS, 0, stream>>>(row, col, ew, dis, t1, fr, E);
            cheb_at_kernel<<<nb, THREADS, 0, stream>>>(fr, t0, outacc, Wc, k, N);
            float2* n0 = t1; float2* n1 = fr; float2* nf = t0;
            t0 = n0; t1 = n1; fr = nf;
        }
    }

    u_ms_kernel<<<nb, THREADS, 0, stream>>>(x, outacc, cb, W, b, U, part, N);
    red_ms_kernel<<<1, 1024, 0, stream>>>(part, nb, scal);
    out_kernel<<<nb, THREADS, 0, stream>>>(U, scal, out, N);
}

// Round 21
// 371.824 us; speedup vs baseline: 1.0213x; 1.0213x over previous
//
#include <hip/hip_runtime.h>
#include <math.h>

#define THREADS 256
#define SB 1024           // blocks for hist/scatter passes (chunked edge ranges)
#define BSH 8             // bucket shift: 256 nodes per bucket
#define BSZ 256
#define BMSK 255
#define SEG 2048          // edges per scatter segment (8 per thread)

// ---------------------------------------------------------------------------
// Per-block LDS histograms over node buckets (bucket = 256 nodes).
__global__ void hist_kernel(const int* __restrict__ row, const int* __restrict__ col,
                            int* __restrict__ TU, int E, int NB, int chunk) {
    extern __shared__ int sh[];
    int t = threadIdx.x, b = blockIdx.x;
    for (int k = t; k < 2 * NB; k += THREADS) sh[k] = 0;
    __syncthreads();
    int lo = b * chunk;
    int hi = min(lo + chunk, E);
    for (int e = lo + t; e < hi; e += THREADS) {
        int r = row[e], c = col[e];
        if (r != c) {
            atomicAdd(&sh[r >> BSH], 1);
            atomicAdd(&sh[NB + (c >> BSH)], 1);
        }
    }
    __syncthreads();
    for (int k = t; k < 2 * NB; k += THREADS) TU[k * SB + b] = sh[k];
}

// ---------------------------------------------------------------------------
// Exclusive scan, 1024 entries per block (4 serial per thread + block scan).
__global__ void scan1_kernel(int* __restrict__ data, int* __restrict__ bsum, int n) {
    __shared__ int s[256];
    int t = threadIdx.x;
    int base = blockIdx.x * 1024 + t * 4;
    int a0 = (base + 0 < n) ? data[base + 0] : 0;
    int a1 = (base + 1 < n) ? data[base + 1] : 0;
    int a2 = (base + 2 < n) ? data[base + 2] : 0;
    int a3 = (base + 3 < n) ? data[base + 3] : 0;
    int tsum = a0 + a1 + a2 + a3;
    s[t] = tsum;
    __syncthreads();
    for (int d = 1; d < 256; d <<= 1) {
        int xv = (t >= d) ? s[t - d] : 0;
        __syncthreads();
        s[t] += xv;
        __syncthreads();
    }
    int excl = s[t] - tsum;
    if (base + 0 < n) data[base + 0] = excl;
    if (base + 1 < n) data[base + 1] = excl + a0;
    if (base + 2 < n) data[base + 2] = excl + a0 + a1;
    if (base + 3 < n) data[base + 3] = excl + a0 + a1 + a2;
    if (t == 255) bsum[blockIdx.x] = s[255];
}

__global__ void scan2_kernel(const int* __restrict__ bsum, int* __restrict__ boff, int nb) {
    __shared__ int s[1024];
    int t = threadIdx.x;
    int v = (t < nb) ? bsum[t] : 0;
    s[t] = v;
    __syncthreads();
    for (int d = 1; d < 1024; d <<= 1) {
        int xv = (t >= d) ? s[t - d] : 0;
        __syncthreads();
        s[t] += xv;
        __syncthreads();
    }
    if (t < nb) boff[t] = s[t] - v;
    if (t == nb - 1) boff[nb] = s[t];            // grand total
}

__global__ void scan3_kernel(int* __restrict__ data, const int* __restrict__ boff,
                             int n, int nbk) {
    int i = blockIdx.x * blockDim.x + threadIdx.x;
    if (i < n) data[i] += boff[i >> 10];
    else if (i == n) data[n] = boff[nbk];        // append grand total
}

// ---------------------------------------------------------------------------
// Scatter with segment-local counting sort (measured-best variant: SEG=2048,
// AoS int2 staging + ushort bid, dense line-filling write-out).
__global__ void scatter_kernel(const int* __restrict__ row, const int* __restrict__ col,
                               const float* __restrict__ ew,
                               const int* __restrict__ TU, int2* __restrict__ rec,
                               int E, int NB, int chunk) {
    extern __shared__ int shl[];
    const int nb2 = 2 * NB;                                    // <= 1024
    int2* staged = (int2*)shl;                                 // [2*SEG]
    int* cur   = shl + 4 * SEG;                                // [nb2]
    int* sbase = cur + nb2;                                    // [nb2]
    int* scur  = sbase + nb2;                                  // [nb2]
    int* stmp  = scur + nb2;                                   // [256]
    unsigned short* bid = (unsigned short*)(stmp + 256);       // [2*SEG]

    int t = threadIdx.x, b = blockIdx.x;
    for (int k = t; k < nb2; k += THREADS) cur[k] = TU[k * SB + b];
    int lo = b * chunk;
    int hi = min(lo + chunk, E);

    for (int slo = lo; slo < hi; slo += SEG) {
        int scount = min(SEG, hi - slo);
        for (int k = t; k < nb2; k += THREADS) sbase[k] = 0;
        __syncthreads();

        int er[8], ec[8];
        float ewv[8];
#pragma unroll
        for (int j = 0; j < 8; ++j) {
            er[j] = -1;
            int e = slo + j * THREADS + t;
            if (e < slo + scount) {
                int r = row[e], c = col[e];
                if (r != c) {
                    er[j] = r; ec[j] = c; ewv[j] = ew[e];
                    atomicAdd(&sbase[r >> BSH], 1);
                    atomicAdd(&sbase[NB + (c >> BSH)], 1);
                }
            }
        }
        __syncthreads();

        // exclusive scan of nb2 per-bucket counts (4 serial + 256 block scan)
        int b4 = t * 4;
        int a0 = (b4 + 0 < nb2) ? sbase[b4 + 0] : 0;
        int a1 = (b4 + 1 < nb2) ? sbase[b4 + 1] : 0;
        int a2 = (b4 + 2 < nb2) ? sbase[b4 + 2] : 0;
        int a3 = (b4 + 3 < nb2) ? sbase[b4 + 3] : 0;
        int tsum = a0 + a1 + a2 + a3;
        stmp[t] = tsum;
        __syncthreads();
        for (int d = 1; d < 256; d <<= 1) {
            int xv = (t >= d) ? stmp[t - d] : 0;
            __syncthreads();
            stmp[t] += xv;
            __syncthreads();
        }
        int excl = stmp[t] - tsum;
        int total = stmp[255];
        __syncthreads();
        if (b4 + 0 < nb2) { sbase[b4 + 0] = excl;                scur[b4 + 0] = excl; }
        if (b4 + 1 < nb2) { sbase[b4 + 1] = excl + a0;           scur[b4 + 1] = excl + a0; }
        if (b4 + 2 < nb2) { sbase[b4 + 2] = excl + a0 + a1;      scur[b4 + 2] = excl + a0 + a1; }
        if (b4 + 3 < nb2) { sbase[b4 + 3] = excl + a0 + a1 + a2; scur[b4 + 3] = excl + a0 + a1 + a2; }
        __syncthreads();

        // ranked placement into bucket-ordered staging
#pragma unroll
        for (int j = 0; j < 8; ++j) {
            if (er[j] >= 0) {
                int r = er[j], c = ec[j];
                int wbits = __float_as_int(ewv[j]);
                int k1 = r >> BSH;
                int p1 = atomicAdd(&scur[k1], 1);
                staged[p1] = make_int2(r & BMSK, wbits);
                bid[p1] = (unsigned short)k1;
                int k2 = NB + (c >> BSH);
                int p2 = atomicAdd(&scur[k2], 1);
                staged[p2] = make_int2((r << BSH) | (c & BMSK), wbits);
                bid[p2] = (unsigned short)k2;
            }
        }
        __syncthreads();

        // cooperative dense write-out (consecutive lanes -> consecutive addrs)
        for (int j = t; j < total; j += THREADS) {
            int k = bid[j];
            rec[cur[k] + (j - sbase[k])] = staged[j];
        }
        __syncthreads();

        for (int k = t; k < nb2; k += THREADS) cur[k] += scur[k] - sbase[k];
        __syncthreads();
    }
}

// ---------------------------------------------------------------------------
// Fused deg-reduce + init: one 1024-thread block per bucket streams the
// bucket's ROW-half records into LDS acc, then finalizes dis/tx0/outacc for
// its 256 nodes.
__global__ void degini_kernel(const int2* __restrict__ rec, const int* __restrict__ TU,
                              const float* __restrict__ x,
                              float* __restrict__ dis, float2* __restrict__ tx0,
                              float2* __restrict__ outacc, const float* __restrict__ Wc,
                              int N) {
    __shared__ float acc[BSZ];
    int t = threadIdx.x, bk = blockIdx.x;
    if (t < BSZ) acc[t] = 0.f;
    __syncthreads();
    int s = TU[bk * SB];
    int e = TU[(bk + 1) * SB];
    int i = s + t;
    for (; i + 3 * 1024 < e; i += 4 * 1024) {
        int2 p0 = rec[i];
        int2 p1 = rec[i + 1024];
        int2 p2 = rec[i + 2048];
        int2 p3 = rec[i + 3072];
        atomicAdd(&acc[p0.x], __int_as_float(p0.y));
        atomicAdd(&acc[p1.x], __int_as_float(p1.y));
        atomicAdd(&acc[p2.x], __int_as_float(p2.y));
        atomicAdd(&acc[p3.x], __int_as_float(p3.y));
    }
    for (; i < e; i += 1024) {
        int2 p = rec[i];
        atomicAdd(&acc[p.x], __int_as_float(p.y));
    }
    __syncthreads();
    if (t < BSZ) {
        int node = (bk << BSH) + t;
        if (node < N) {
            float d = acc[t];
            dis[node] = (d > 0.f) ? rsqrtf(d) : 0.f;
            float x0 = x[3 * node + 0];
            float x1 = x[3 * node + 1];
            tx0[node] = make_float2(x0, x1);
            outacc[node] = make_float2(x0 * Wc[0] + x1 * Wc[2],
                                       x0 * Wc[1] + x1 * Wc[3]);
        }
    }
}

// ---------------------------------------------------------------------------
// Node-level sort of the COL half + norm baking + FUSED PASS-1 PROPAGATION
// (measured-best simple strided form). Sorted {r_global, norm} records land
// in the row-half region of rec (dead after degini).
__global__ void nodesort_kernel(const int2* __restrict__ rec, const int* __restrict__ TU,
                                const float* __restrict__ dis, const float2* __restrict__ hA,
                                int2* __restrict__ srec, int* __restrict__ rowstart,
                                float2* __restrict__ vout, float2* __restrict__ outacc,
                                const float* __restrict__ Wc, int NB, int N) {
    __shared__ int cnt[BSZ], cur[BSZ], stmp[BSZ];
    __shared__ float disc[BSZ], ax[BSZ], ay[BSZ];
    int t = threadIdx.x, bk = blockIdx.x;
    int colbase = TU[NB * SB];
    if (t < BSZ) {
        cnt[t] = 0;
        ax[t] = 0.f;
        ay[t] = 0.f;
        int node = (bk << BSH) + t;
        disc[t] = (node < N) ? dis[node] : 0.f;
    }
    __syncthreads();
    int s = TU[(NB + bk) * SB];
    int e = TU[(NB + bk + 1) * SB];
    for (int i = s + t; i < e; i += 1024) atomicAdd(&cnt[rec[i].x & BMSK], 1);
    __syncthreads();
    if (t < BSZ) stmp[t] = cnt[t];
    __syncthreads();
    for (int d = 1; d < BSZ; d <<= 1) {
        int xv = (t >= d && t < BSZ) ? stmp[t - d] : 0;
        __syncthreads();
        if (t < BSZ) stmp[t] += xv;
        __syncthreads();
    }
    if (t < BSZ) {
        int g = (s - colbase) + stmp[t] - cnt[t];
        cur[t] = g;
        rowstart[(bk << BSH) + t] = g;
        if (bk == NB - 1 && t == 0) rowstart[NB << BSH] = e - colbase;
    }
    __syncthreads();
    for (int i = s + t; i < e; i += 1024) {
        int2 p = rec[i];
        int cl = p.x & BMSK;
        int r = ((unsigned)p.x) >> BSH;
        float w = -dis[r] * __int_as_float(p.y) * disc[cl];
        int pos = atomicAdd(&cur[cl], 1);
        srec[pos] = make_int2(r, __float_as_int(w));
        float2 hv = hA[r];
        atomicAdd(&ax[cl], w * hv.x);
        atomicAdd(&ay[cl], w * hv.y);
    }
    __syncthreads();
    if (t < BSZ) {
        int node = (bk << BSH) + t;
        if (node < N) {
            float2 v = make_float2(ax[t], ay[t]);       // Tx1 (k=1: no recurrence)
            vout[node] = v;
            float2 o = outacc[node];
            o.x += v.x * Wc[4 + 0] + v.y * Wc[4 + 2];   // Wc[1]
            o.y += v.x * Wc[4 + 1] + v.y * Wc[4 + 3];
            outacc[node] = o;
        }
    }
}

// ---------------------------------------------------------------------------
// Propagation with fused Chebyshev update (k>=2): 16 lanes per node, simple
// strided record loop (measured-best form), width-16 shuffle reduce.
__global__ void gather_kernel(const int2* __restrict__ srec, const int* __restrict__ rowstart,
                              const float2* __restrict__ h, const float2* __restrict__ tx0,
                              float2* __restrict__ vout, float2* __restrict__ outacc,
                              const float* __restrict__ Wc, int k, int N) {
    int g = blockIdx.x * (THREADS / 16) + (threadIdx.x >> 4);
    int lane = threadIdx.x & 15;
    if (g >= N) return;
    int s = rowstart[g];
    int e = rowstart[g + 1];
    float sx = 0.f, sy = 0.f;
    for (int i = s + lane; i < e; i += 16) {
        int2 p = srec[i];
        float2 hv = h[p.x];
        float w = __int_as_float(p.y);
        sx = fmaf(w, hv.x, sx);
        sy = fmaf(w, hv.y, sy);
    }
    for (int off = 8; off > 0; off >>= 1) {
        sx += __shfl_down(sx, off, 16);
        sy += __shfl_down(sy, off, 16);
    }
    if (lane == 0) {
        float2 v = make_float2(sx, sy);
        if (tx0) {
            float2 tv = tx0[g];
            v.x = 2.f * v.x - tv.x;
            v.y = 2.f * v.y - tv.y;
        }
        vout[g] = v;
        float2 o = outacc[g];
        o.x += v.x * Wc[4 * k + 0] + v.y * Wc[4 * k + 2];
        o.y += v.x * Wc[4 * k + 1] + v.y * Wc[4 * k + 3];
        outacc[g] = o;
    }
}

// ---------------------------------------------------------------------------
// Full-atomic fallback kernels (only if workspace is too small).
__global__ void zero_kernel(float* __restrict__ p, int n) {
    int i = blockIdx.x * blockDim.x + threadIdx.x;
    if (i < n) p[i] = 0.f;
}
__global__ void zerof2_kernel(float2* __restrict__ p, int n) {
    int i = blockIdx.x * blockDim.x + threadIdx.x;
    if (i < n) p[i] = make_float2(0.f, 0.f);
}
__global__ void deg_at_kernel(const int* __restrict__ row, const int* __restrict__ col,
                              const float* __restrict__ ew, float* __restrict__ deg, int E) {
    int e = blockIdx.x * blockDim.x + threadIdx.x;
    if (e >= E) return;
    int r = row[e], c = col[e];
    if (r != c) atomicAdd(&deg[r], ew[e]);
}
__global__ void init_at_kernel(const float* __restrict__ x, float* __restrict__ deg,
                               float2* __restrict__ tx0, float2* __restrict__ outacc,
                               const float* __restrict__ Wc, int N) {
    int i = blockIdx.x * blockDim.x + threadIdx.x;
    if (i >= N) return;
    float d = deg[i];
    deg[i] = (d > 0.f) ? rsqrtf(d) : 0.f;
    float x0 = x[3 * i + 0];
    float x1 = x[3 * i + 1];
    tx0[i] = make_float2(x0, x1);
    outacc[i] = make_float2(x0 * Wc[0] + x1 * Wc[2],
                            x0 * Wc[1] + x1 * Wc[3]);
}
__global__ void prop_kernel(const int* __restrict__ row, const int* __restrict__ col,
                            const float* __restrict__ ew, const float* __restrict__ dis,
                            const float2* __restrict__ h, float2* __restrict__ o, int E) {
    int e = blockIdx.x * blockDim.x + threadIdx.x;
    if (e >= E) return;
    int r = row[e], c = col[e];
    if (r == c) return;
    float w = -dis[r] * ew[e] * dis[c];
    if (w == 0.f) return;
    float2 hv = h[r];
    atomicAdd(&o[c].x, w * hv.x);
    atomicAdd(&o[c].y, w * hv.y);
}
__global__ void cheb_at_kernel(float2* __restrict__ raw, const float2* __restrict__ tx0,
                               float2* __restrict__ outacc, const float* __restrict__ Wc,
                               int k, int N) {
    int i = blockIdx.x * blockDim.x + threadIdx.x;
    if (i >= N) return;
    float2 v = raw[i];
    if (tx0) {
        float2 t = tx0[i];
        v.x = 2.f * v.x - t.x;
        v.y = 2.f * v.y - t.y;
        raw[i] = v;
    }
    float2 o = outacc[i];
    o.x += v.x * Wc[4 * k + 0] + v.y * Wc[4 * k + 2];
    o.y += v.x * Wc[4 * k + 1] + v.y * Wc[4 * k + 3];
    outacc[i] = o;
}

// ---------------------------------------------------------------------------
// Fused epilogue (3 kernels): per-block (max, sum-of-exp) via LSE rescale.
__global__ void u_ms_kernel(const float* __restrict__ x, const float2* __restrict__ outacc,
                            const float* __restrict__ cb, const float* __restrict__ W,
                            const float* __restrict__ b, float* __restrict__ U,
                            float* __restrict__ part2, int N) {
    __shared__ float sm[THREADS / 64];
    __shared__ float bmax;
    int i = blockIdx.x * blockDim.x + threadIdx.x;
    int t = threadIdx.x;
    float u = -INFINITY;
    if (i < N) {
        float2 o = outacc[i];
        float h0 = fmaxf(o.x + cb[0], 0.f);
        float h1 = fmaxf(o.y + cb[1], 0.f);
        u = x[3 * i + 2] * W[0] + h0 * W[1] + h1 * W[2] + b[0];
        U[i] = u;
    }
    float mv = u;
    for (int off = 32; off > 0; off >>= 1) mv = fmaxf(mv, __shfl_down(mv, off));
    if ((t & 63) == 0) sm[t >> 6] = mv;
    __syncthreads();
    if (t == 0) {
        float m = sm[0];
        for (int w = 1; w < THREADS / 64; ++w) m = fmaxf(m, sm[w]);
        bmax = m;
    }
    __syncthreads();
    float bm = bmax;
    float e = (i < N) ? expf(u - bm) : 0.f;
    for (int off = 32; off > 0; off >>= 1) e += __shfl_down(e, off);
    __syncthreads();
    if ((t & 63) == 0) sm[t >> 6] = e;
    __syncthreads();
    if (t == 0) {
        float s = sm[0];
        for (int w = 1; w < THREADS / 64; ++w) s += sm[w];
        part2[2 * blockIdx.x]     = bm;
        part2[2 * blockIdx.x + 1] = s;
    }
}

__global__ void red_ms_kernel(const float* __restrict__ part2, int n,
                              float* __restrict__ scal) {
    __shared__ float sm[16];
    __shared__ float gmax;
    int t = threadIdx.x;
    float m = -INFINITY;
    for (int i = t; i < n; i += blockDim.x) m = fmaxf(m, part2[2 * i]);
    for (int off = 32; off > 0; off >>= 1) m = fmaxf(m, __shfl_down(m, off));
    int wid = t >> 6;
    if ((t & 63) == 0) sm[wid] = m;
    __syncthreads();
    if (t == 0) {
        float r = sm[0];
        int nw = blockDim.x >> 6;
        for (int w = 1; w < nw; ++w) r = fmaxf(r, sm[w]);
        gmax = r;
    }
    __syncthreads();
    float M = gmax;
    float s = 0.f;
    for (int i = t; i < n; i += blockDim.x) s += part2[2 * i + 1] * expf(part2[2 * i] - M);
    for (int off = 32; off > 0; off >>= 1) s += __shfl_down(s, off);
    __syncthreads();
    if ((t & 63) == 0) sm[wid] = s;
    __syncthreads();
    if (t == 0) {
        float r = sm[0];
        int nw = blockDim.x >> 6;
        for (int w = 1; w < nw; ++w) r += sm[w];
        scal[0] = M;
        scal[1] = 1.f / r;
    }
}

__global__ void out_kernel(const float* __restrict__ U, const float* __restrict__ scal,
                           float* __restrict__ out, int N) {
    int i = blockIdx.x * blockDim.x + threadIdx.x;
    if (i < N) out[i] = expf(U[i] - scal[0]) * scal[1];
}

// ---------------------------------------------------------------------------
extern "C" void kernel_launch(void* const* d_in, const int* in_sizes, int n_in,
                              void* d_out, int out_size, void* d_ws, size_t ws_size,
                              hipStream_t stream) {
    (void)n_in; (void)out_size;
    const float* x    = (const float*)d_in[0];
    const int*   eidx = (const int*)d_in[1];     // int32 per harness contract
    const float* ew   = (const float*)d_in[2];
    const float* Wc   = (const float*)d_in[3];
    const float* cb   = (const float*)d_in[4];
    const float* W    = (const float*)d_in[5];
    const float* b    = (const float*)d_in[6];
    float*       out  = (float*)d_out;

    const int N = in_sizes[0] / 3;
    const int E = in_sizes[2];
    const int K = in_sizes[3] / 4;
    const int* row = eidx;
    const int* col = eidx + E;

    const int NB    = (N + BMSK) >> BSH;         // 256-node buckets
    const int nb2   = 2 * NB;
    const int n2    = nb2 * SB;                  // unified count-table length
    const int nblk  = (n2 + 1023) / 1024;        // scan1 blocks (1024/block)
    const int chunk = (E + SB - 1) / SB;
    const int Npad  = NB << BSH;

    char* ws = (char*)d_ws;
    size_t off = 0;
    auto take = [&](size_t bytes) -> void* {
        void* p = ws + off;
        off = (off + bytes + 255) & ~(size_t)255;
        return p;
    };

    float*  dis      = (float*)take((size_t)N * 4);
    float2* A        = (float2*)take((size_t)N * 8);
    float2* B        = (float2*)take((size_t)N * 8);
    float2* C        = (float2*)take((size_t)N * 8);
    float2* outacc   = (float2*)take((size_t)N * 8);
    float*  U        = (float*)take((size_t)N * 4);
    float*  part     = (float*)take(8192 * 4);
    float*  scal     = (float*)take(64 * 4);
    int*    TU       = (int*)take((size_t)(n2 + 1) * 4);
    int*    bsum     = (int*)take(1024 * 4);
    int*    boff     = (int*)take(1025 * 4);
    int*    rowstart = (int*)take((size_t)(Npad + 1) * 4);
    int2*   rec      = (int2*)take((size_t)2 * E * 8);

    const bool bucket_ok = (nb2 <= 1024) && (nblk <= 1024) && (N < (1 << 23)) &&
                           (off <= ws_size) && (K >= 2);

    const int eb = (E + THREADS - 1) / THREADS;
    const int nb = (N + THREADS - 1) / THREADS;

    if (bucket_ok) {
        // dynamic LDS for scatter (must match device-side layout)
        size_t scat_lds = (size_t)(4 * SEG) * 4      // staged int2[2*SEG]
                        + (size_t)(3 * nb2) * 4      // cur/sbase/scur
                        + 256 * 4                    // stmp
                        + (size_t)(2 * SEG) * 2;     // bid ushort

        hist_kernel<<<SB, THREADS, nb2 * 4, stream>>>(row, col, TU, E, NB, chunk);
        scan1_kernel<<<nblk, 256, 0, stream>>>(TU, bsum, n2);
        scan2_kernel<<<1, 1024, 0, stream>>>(bsum, boff, nblk);
        scan3_kernel<<<(n2 + 256) / 256, 256, 0, stream>>>(TU, boff, n2, nblk);
        scatter_kernel<<<SB, THREADS, scat_lds, stream>>>(row, col, ew, TU, rec, E, NB, chunk);
        // fused deg-reduce + init (row half)
        degini_kernel<<<NB, 1024, 0, stream>>>(rec, TU, x, dis, A, outacc, Wc, N);
        // node sort + norm bake + fused pass-1 prop + cheb k=1 (col half -> row-half region)
        nodesort_kernel<<<NB, 1024, 0, stream>>>(rec, TU, dis, A, rec, rowstart,
                                                 B, outacc, Wc, NB, N);

        const int gb = (N + (THREADS / 16) - 1) / (THREADS / 16);
        // k = 2..K-1, Chebyshev update fused into gather epilogue
        float2 *t0 = A, *t1 = B, *fr = C;
        for (int k = 2; k < K; ++k) {
            gather_kernel<<<gb, THREADS, 0, stream>>>(rec, rowstart, t1, t0, fr, outacc, Wc, k, N);
            float2* n0 = t1; float2* n1 = fr; float2* nf = t0;
            t0 = n0; t1 = n1; fr = nf;
        }
    } else {
        // ---- full-atomic fallback ----
        zero_kernel<<<nb, THREADS, 0, stream>>>(dis, N);
        deg_at_kernel<<<eb, THREADS, 0, stream>>>(row, col, ew, dis, E);
        init_at_kernel<<<nb, THREADS, 0, stream>>>(x, dis, A, outacc, Wc, N);
        zerof2_kernel<<<nb, THREADS, 0, stream>>>(B, N);
        prop_kernel<<<eb, THREADS, 0, stream>>>(row, col, ew, dis, A, B, E);
        cheb_at_kernel<<<nb, THREADS, 0, stream>>>(B, (const float2*)nullptr, outacc, Wc, 1, N);
        float2 *t0 = A, *t1 = B, *fr = C;
        for (int k = 2; k < K; ++k) {
            zerof2_kernel<<<nb, THREADS, 0, stream>>>(fr, N);
            prop_kernel<<<eb, THREADS, 0, stream>>>(row, col, ew, dis, t1, fr, E);
            cheb_at_kernel<<<nb, THREADS, 0, stream>>>(fr, t0, outacc, Wc, k, N);
            float2* n0 = t1; float2* n1 = fr; float2* nf = t0;
            t0 = n0; t1 = n1; fr = nf;
        }
    }

    u_ms_kernel<<<nb, THREADS, 0, stream>>>(x, outacc, cb, W, b, U, part, N);
    red_ms_kernel<<<1, 1024, 0, stream>>>(part, nb, scal);
    out_kernel<<<nb, THREADS, 0, stream>>>(U, scal, out, N);
}